// Round 5
// baseline (1595.250 us; speedup 1.0000x reference)
//
#include <hip/hip_runtime.h>
#include <hip/hip_bf16.h>

#define NN 100000
#define NE 1600000
#define HID 512
#define LOW 128
#define NR  6
#define NBINS (NN * NR)

typedef short  bf16x8 __attribute__((ext_vector_type(8)));
typedef float  f32x4  __attribute__((ext_vector_type(4)));

__device__ __forceinline__ unsigned short f2bf(float x) {
    __hip_bfloat16 h = __float2bfloat16(x);
    return __builtin_bit_cast(unsigned short, h);
}
__device__ __forceinline__ float bf2f(unsigned short u) {
    return __builtin_bit_cast(float, (unsigned int)u << 16);
}

// ---------------------------------------------------------------------------
// Tile staging for 128B-row tiles (gemm_bf16 / gemm_out_fused): LDS [128][64]
// bf16, 8 chunks/row, XOR-swizzle by (row&7) via pre-swizzled SOURCE.
// ---------------------------------------------------------------------------
__device__ __forceinline__ void stage_tile(const unsigned short* __restrict__ G,
                                           int r0, int k0, int Kstride, int Rmax,
                                           char* lds_base, int tid)
{
    #pragma unroll
    for (int is = 0; is < 4; ++is) {
        int L   = is * 4096 + tid * 16;
        int row = L >> 7;
        int c   = ((L >> 4) & 7) ^ (row & 7);
        int gr  = r0 + row;
        gr = (gr < Rmax) ? gr : (Rmax - 1);
        const char* src = (const char*)G + ((size_t)gr * Kstride + k0) * 2 + c * 16;
        __builtin_amdgcn_global_load_lds(
            (const __attribute__((address_space(1))) void*)src,
            (__attribute__((address_space(3))) void*)(lds_base + is * 4096 + (tid & 192) * 16),
            16, 0, 0);
    }
}

__device__ __forceinline__ bf16x8 lds_frag(const char* lds_base, int row, int clog)
{
    return *(const bf16x8*)(lds_base + row * 128 + ((clog ^ (row & 7)) << 4));
}

// 256B-row variant (rgcn_layer): 16 chunks/row, XOR by (row&15).
__device__ __forceinline__ bf16x8 lds_frag16(const char* lds_base, int row, int clog)
{
    return *(const bf16x8*)(lds_base + row * 256 + ((clog ^ (row & 15)) << 4));
}

// ---------------------------------------------------------------------------
// bf16 MFMA GEMM: C(bf16) = relu(A @ Bt^T + bias). 128x128 tile, 4 waves.
// ---------------------------------------------------------------------------
__global__ __launch_bounds__(256, 2)
void gemm_bf16(const unsigned short* __restrict__ A,
               const unsigned short* __restrict__ Bt,
               const float* __restrict__ bias,
               unsigned short* __restrict__ C,
               int M, int N, int K)
{
    __shared__ __align__(16) char lA[16384];
    __shared__ __align__(16) char lB[16384];

    const int tid  = threadIdx.x;
    const int lane = tid & 63;
    const int wid  = tid >> 6;
    const int wm   = wid >> 1;
    const int wn   = wid & 1;
    const int m0   = blockIdx.y * 128;
    const int n0   = blockIdx.x * 128;

    f32x4 acc[4][4] = {};

    for (int k0 = 0; k0 < K; k0 += 64) {
        stage_tile(A,  m0, k0, K, M, lA, tid);
        stage_tile(Bt, n0, k0, K, N, lB, tid);
        __syncthreads();
        #pragma unroll
        for (int kk = 0; kk < 2; ++kk) {
            const int clog = kk * 4 + (lane >> 4);
            bf16x8 af[4], bfr[4];
            #pragma unroll
            for (int i = 0; i < 4; ++i)
                af[i] = lds_frag(lA, wm * 64 + i * 16 + (lane & 15), clog);
            #pragma unroll
            for (int j = 0; j < 4; ++j)
                bfr[j] = lds_frag(lB, wn * 64 + j * 16 + (lane & 15), clog);
            #pragma unroll
            for (int i = 0; i < 4; ++i)
                #pragma unroll
                for (int j = 0; j < 4; ++j)
                    acc[i][j] = __builtin_amdgcn_mfma_f32_16x16x32_bf16(
                        af[i], bfr[j], acc[i][j], 0, 0, 0);
        }
        __syncthreads();
    }

    const int col_l = lane & 15;
    const int rgrp  = lane >> 4;
    #pragma unroll
    for (int i = 0; i < 4; ++i) {
        #pragma unroll
        for (int j = 0; j < 4; ++j) {
            int col  = n0 + wn * 64 + j * 16 + col_l;
            float bv = bias[col];
            #pragma unroll
            for (int r = 0; r < 4; ++r) {
                int row = m0 + wm * 64 + i * 16 + rgrp * 4 + r;
                if (row < M)
                    C[(size_t)row * N + col] = f2bf(fmaxf(acc[i][j][r] + bv, 0.f));
            }
        }
    }
}

// ---------------------------------------------------------------------------
// Fused output: out(f32) = relu(h @ Wut^T + bu) + relu(hob @ Wst^T + bs)
// ---------------------------------------------------------------------------
__global__ __launch_bounds__(256, 2)
void gemm_out_fused(const unsigned short* __restrict__ h,
                    const unsigned short* __restrict__ Wut,
                    const float* __restrict__ bu,
                    const unsigned short* __restrict__ hob,
                    const unsigned short* __restrict__ Wst,
                    const float* __restrict__ bs,
                    float* __restrict__ out, int M)
{
    __shared__ __align__(16) char lA[16384];
    __shared__ __align__(16) char lB[16384];

    const int tid  = threadIdx.x;
    const int lane = tid & 63;
    const int wid  = tid >> 6;
    const int wm   = wid >> 1;
    const int wn   = wid & 1;
    const int m0   = blockIdx.y * 128;
    const int n0   = blockIdx.x * 128;

    f32x4 acc1[4][4] = {};
    f32x4 acc2[4][4] = {};

    for (int k0 = 0; k0 < LOW; k0 += 64) {
        stage_tile(h,   m0, k0, LOW, M,   lA, tid);
        stage_tile(Wut, n0, k0, LOW, HID, lB, tid);
        __syncthreads();
        #pragma unroll
        for (int kk = 0; kk < 2; ++kk) {
            const int clog = kk * 4 + (lane >> 4);
            bf16x8 af[4], bfr[4];
            #pragma unroll
            for (int i = 0; i < 4; ++i)
                af[i] = lds_frag(lA, wm * 64 + i * 16 + (lane & 15), clog);
            #pragma unroll
            for (int j = 0; j < 4; ++j)
                bfr[j] = lds_frag(lB, wn * 64 + j * 16 + (lane & 15), clog);
            #pragma unroll
            for (int i = 0; i < 4; ++i)
                #pragma unroll
                for (int j = 0; j < 4; ++j)
                    acc1[i][j] = __builtin_amdgcn_mfma_f32_16x16x32_bf16(
                        af[i], bfr[j], acc1[i][j], 0, 0, 0);
        }
        __syncthreads();
    }
    for (int k0 = 0; k0 < HID; k0 += 64) {
        stage_tile(hob, m0, k0, HID, M,   lA, tid);
        stage_tile(Wst, n0, k0, HID, HID, lB, tid);
        __syncthreads();
        #pragma unroll
        for (int kk = 0; kk < 2; ++kk) {
            const int clog = kk * 4 + (lane >> 4);
            bf16x8 af[4], bfr[4];
            #pragma unroll
            for (int i = 0; i < 4; ++i)
                af[i] = lds_frag(lA, wm * 64 + i * 16 + (lane & 15), clog);
            #pragma unroll
            for (int j = 0; j < 4; ++j)
                bfr[j] = lds_frag(lB, wn * 64 + j * 16 + (lane & 15), clog);
            #pragma unroll
            for (int i = 0; i < 4; ++i)
                #pragma unroll
                for (int j = 0; j < 4; ++j)
                    acc2[i][j] = __builtin_amdgcn_mfma_f32_16x16x32_bf16(
                        af[i], bfr[j], acc2[i][j], 0, 0, 0);
        }
        __syncthreads();
    }

    const int col_l = lane & 15;
    const int rgrp  = lane >> 4;
    #pragma unroll
    for (int i = 0; i < 4; ++i) {
        #pragma unroll
        for (int j = 0; j < 4; ++j) {
            int col   = n0 + wn * 64 + j * 16 + col_l;
            float bv1 = bu[col], bv2 = bs[col];
            #pragma unroll
            for (int r = 0; r < 4; ++r) {
                int row = m0 + wm * 64 + i * 16 + rgrp * 4 + r;
                if (row < M)
                    out[(size_t)row * HID + col] =
                        fmaxf(acc1[i][j][r] + bv1, 0.f) + fmaxf(acc2[i][j][r] + bv2, 0.f);
            }
        }
    }
}

// ---------------------------------------------------------------------------
// FUSED R-GCN layer: per 128-node tile, for each relation r: gather S_r tile
// into LDS (4 concurrent edge-chains per wave for MLP), stage W_r via
// global_load_lds, then MFMA-accumulate. Epilogue: relu(acc + bias) -> hn.
// LDS tiles use 16-chunk XOR swizzle (row&15).
// ---------------------------------------------------------------------------
__global__ __launch_bounds__(256, 2)
void rgcn_layer(const unsigned short* __restrict__ h,
                const int* __restrict__ rowstart,
                const int* __restrict__ list,
                const unsigned short* __restrict__ wt,   // [128][768] bf16, K-contig
                const float* __restrict__ bias,
                unsigned short* __restrict__ hn)
{
    __shared__ __align__(16) char lS[32768];   // S_r tile [128][128ch] bf16
    __shared__ __align__(16) char lW[32768];   // W_r tile [128][128ch] bf16
    __shared__ int sbound[772];

    const int tid  = threadIdx.x;
    const int lane = tid & 63;
    const int wid  = tid >> 6;
    const int wm   = wid >> 1;
    const int wn   = wid & 1;
    const int v0   = blockIdx.x * 128;
    const ushort2* hp = (const ushort2*)h;

    // Stage per-node segment boundaries: sbound[j] = rowstart[v0*6 + j], j<769
    for (int j = tid; j < 769; j += 256) {
        int gidx = v0 * NR + j;
        sbound[j] = rowstart[(gidx <= NBINS) ? gidx : NBINS];
    }
    __syncthreads();

    f32x4 acc[4][4] = {};

    for (int r = 0; r < NR; ++r) {
        // ---- stage W_r tile: rows=out-ch, 256B = in-ch slice [r*128,(r+1)*128)
        #pragma unroll
        for (int is = 0; is < 8; ++is) {
            int L    = is * 4096 + tid * 16;
            int row  = L >> 8;
            int cg   = ((L >> 4) & 15) ^ (row & 15);
            const char* src = (const char*)wt + ((size_t)row * (NR * LOW) + r * LOW + cg * 8) * 2;
            __builtin_amdgcn_global_load_lds(
                (const __attribute__((address_space(1))) void*)src,
                (__attribute__((address_space(3))) void*)(lW + is * 4096 + (tid & 192) * 16),
                16, 0, 0);
        }

        // ---- gather S_r: wave handles 32 nodes, 4 concurrent chains ----
        for (int g = 0; g < 8; ++g) {
            const int tA = wid * 32 + g;
            const int tB = tA + 8, tC = tA + 16, tD = tA + 24;
            const int sA = sbound[tA * NR + r], eA = sbound[tA * NR + r + 1];
            const int sB = sbound[tB * NR + r], eB = sbound[tB * NR + r + 1];
            const int sC = sbound[tC * NR + r], eC = sbound[tC * NR + r + 1];
            const int sD = sbound[tD * NR + r], eD = sbound[tD * NR + r + 1];
            const int nA = eA - sA, nB = eB - sB, nC = eC - sC, nD = eD - sD;
            int kmax = max(max(nA, nB), max(nC, nD));

            float axA = 0.f, ayA = 0.f, axB = 0.f, ayB = 0.f;
            float axC = 0.f, ayC = 0.f, axD = 0.f, ayD = 0.f;

            for (int k = 0; k < kmax; ++k) {
                // clamped indices keep every load valid; wasted loads hit hot lines
                int iA = (k < nA) ? (sA + k) : 0;
                int iB = (k < nB) ? (sB + k) : 0;
                int iC = (k < nC) ? (sC + k) : 0;
                int iD = (k < nD) ? (sD + k) : 0;
                int srcA = list[iA], srcB = list[iB], srcC = list[iC], srcD = list[iD];
                ushort2 uA = hp[(size_t)srcA * 64 + lane];
                ushort2 uB = hp[(size_t)srcB * 64 + lane];
                ushort2 uC = hp[(size_t)srcC * 64 + lane];
                ushort2 uD = hp[(size_t)srcD * 64 + lane];
                axA += (k < nA) ? bf2f(uA.x) : 0.f;  ayA += (k < nA) ? bf2f(uA.y) : 0.f;
                axB += (k < nB) ? bf2f(uB.x) : 0.f;  ayB += (k < nB) ? bf2f(uB.y) : 0.f;
                axC += (k < nC) ? bf2f(uC.x) : 0.f;  ayC += (k < nC) ? bf2f(uC.y) : 0.f;
                axD += (k < nD) ? bf2f(uD.x) : 0.f;  ayD += (k < nD) ? bf2f(uD.y) : 0.f;
            }

            // ds_write channel-pair (4B) with the 16-chunk swizzle
            const int coff = (((lane >> 2)) << 4) * 0 + ((lane & 3) << 2); // byte-in-chunk
            const int cl   = lane >> 2;                                    // logical chunk
            {
                unsigned pA = (unsigned)f2bf(axA) | ((unsigned)f2bf(ayA) << 16);
                *(unsigned*)(lS + tA * 256 + ((cl ^ (tA & 15)) << 4) + coff) = pA;
                unsigned pB = (unsigned)f2bf(axB) | ((unsigned)f2bf(ayB) << 16);
                *(unsigned*)(lS + tB * 256 + ((cl ^ (tB & 15)) << 4) + coff) = pB;
                unsigned pC = (unsigned)f2bf(axC) | ((unsigned)f2bf(ayC) << 16);
                *(unsigned*)(lS + tC * 256 + ((cl ^ (tC & 15)) << 4) + coff) = pC;
                unsigned pD = (unsigned)f2bf(axD) | ((unsigned)f2bf(ayD) << 16);
                *(unsigned*)(lS + tD * 256 + ((cl ^ (tD & 15)) << 4) + coff) = pD;
            }
        }
        __syncthreads();   // S_r + W_r ready (drains global_load_lds too)

        // ---- MFMA: acc += S_r @ W_r^T (K = 128) ----
        #pragma unroll
        for (int kk = 0; kk < 4; ++kk) {
            const int clog = kk * 4 + (lane >> 4);
            bf16x8 af[4], bfr[4];
            #pragma unroll
            for (int i = 0; i < 4; ++i)
                af[i] = lds_frag16(lS, wm * 64 + i * 16 + (lane & 15), clog);
            #pragma unroll
            for (int j = 0; j < 4; ++j)
                bfr[j] = lds_frag16(lW, wn * 64 + j * 16 + (lane & 15), clog);
            #pragma unroll
            for (int i = 0; i < 4; ++i)
                #pragma unroll
                for (int j = 0; j < 4; ++j)
                    acc[i][j] = __builtin_amdgcn_mfma_f32_16x16x32_bf16(
                        af[i], bfr[j], acc[i][j], 0, 0, 0);
        }
        __syncthreads();   // MFMA reads done before next r overwrites tiles
    }

    // ---- epilogue: hn = relu(acc + bias) ----
    const int col_l = lane & 15;
    const int rgrp  = lane >> 4;
    #pragma unroll
    for (int i = 0; i < 4; ++i) {
        #pragma unroll
        for (int j = 0; j < 4; ++j) {
            int col  = wn * 64 + j * 16 + col_l;
            float bv = bias[col];
            #pragma unroll
            for (int rr = 0; rr < 4; ++rr) {
                int row = v0 + wm * 64 + i * 16 + rgrp * 4 + rr;
                if (row < NN)
                    hn[(size_t)row * LOW + col] = f2bf(fmaxf(acc[i][j][rr] + bv, 0.f));
            }
        }
    }
}

// ---------------------------------------------------------------------------
// Conversions
// ---------------------------------------------------------------------------
__global__ __launch_bounds__(256)
void conv_f32_bf16(const float4* __restrict__ in, ushort4* __restrict__ out, int n4)
{
    for (int i = blockIdx.x * 256 + threadIdx.x; i < n4; i += gridDim.x * 256) {
        float4 v = in[i];
        ushort4 o;
        o.x = f2bf(v.x); o.y = f2bf(v.y); o.z = f2bf(v.z); o.w = f2bf(v.w);
        out[i] = o;
    }
}

__global__ __launch_bounds__(256)
void transpose_bf16(const float* __restrict__ W, unsigned short* __restrict__ Wt,
                    int R, int C)
{
    int idx = blockIdx.x * 256 + threadIdx.x;
    if (idx < R * C) {
        int r = idx / C, c = idx - r * C;
        Wt[(size_t)c * R + r] = f2bf(W[idx]);
    }
}

// ---------------------------------------------------------------------------
// CSR build keyed by bin = dst*NR + rel. Parallel 3-kernel exclusive scan.
// ---------------------------------------------------------------------------
#define SCAN_VT 8
#define SCAN_BS 256
#define SCAN_CHUNK (SCAN_VT * SCAN_BS)
#define SCAN_NB ((NBINS + SCAN_CHUNK - 1) / SCAN_CHUNK)

__global__ __launch_bounds__(256)
void k_hist(const int* __restrict__ dst, const int* __restrict__ typ,
            int* __restrict__ deg, int E)
{
    int e = blockIdx.x * 256 + threadIdx.x;
    if (e < E) atomicAdd(&deg[dst[e] * NR + typ[e]], 1);
}

__global__ __launch_bounds__(SCAN_BS)
void k_scan_part(const int* __restrict__ deg, int* __restrict__ blocksum, int n)
{
    __shared__ int ps[SCAN_BS];
    const int t = threadIdx.x;
    const int lo = blockIdx.x * SCAN_CHUNK + t * SCAN_VT;
    int s = 0;
    #pragma unroll
    for (int k = 0; k < SCAN_VT; ++k) {
        int i = lo + k;
        if (i < n) s += deg[i];
    }
    ps[t] = s;
    __syncthreads();
    for (int off = SCAN_BS / 2; off > 0; off >>= 1) {
        if (t < off) ps[t] += ps[t + off];
        __syncthreads();
    }
    if (t == 0) blocksum[blockIdx.x] = ps[0];
}

__global__ __launch_bounds__(64)
void k_scan_mid(const int* __restrict__ blocksum, int* __restrict__ blockoff,
                int* __restrict__ rowstart, int nb, int n)
{
    if (threadIdx.x == 0) {
        int run = 0;
        for (int i = 0; i < nb; ++i) { blockoff[i] = run; run += blocksum[i]; }
        rowstart[n] = run;
    }
}

__global__ __launch_bounds__(SCAN_BS)
void k_scan_final(const int* __restrict__ deg, const int* __restrict__ blockoff,
                  int* __restrict__ rowstart, int* __restrict__ cursor, int n)
{
    __shared__ int ps[SCAN_BS];
    const int t = threadIdx.x;
    const int lo = blockIdx.x * SCAN_CHUNK + t * SCAN_VT;
    int local[SCAN_VT];
    int s = 0;
    #pragma unroll
    for (int k = 0; k < SCAN_VT; ++k) {
        int i = lo + k;
        int v = (i < n) ? deg[i] : 0;
        local[k] = v;
        s += v;
    }
    ps[t] = s;
    __syncthreads();
    for (int off = 1; off < SCAN_BS; off <<= 1) {
        int v = (t >= off) ? ps[t - off] : 0;
        __syncthreads();
        ps[t] += v;
        __syncthreads();
    }
    int run = blockoff[blockIdx.x] + ((t > 0) ? ps[t - 1] : 0);
    #pragma unroll
    for (int k = 0; k < SCAN_VT; ++k) {
        int i = lo + k;
        if (i < n) {
            rowstart[i] = run;
            cursor[i]   = run;
            run += local[k];
        }
    }
}

__global__ __launch_bounds__(256)
void k_fill(const int* __restrict__ src, const int* __restrict__ dst,
            const int* __restrict__ typ, int* __restrict__ cursor,
            int* __restrict__ list, int E)
{
    int e = blockIdx.x * 256 + threadIdx.x;
    if (e < E) {
        int pos = atomicAdd(&cursor[dst[e] * NR + typ[e]], 1);
        list[pos] = src[e];
    }
}

extern "C" void kernel_launch(void* const* d_in, const int* in_sizes, int n_in,
                              void* d_out, int out_size, void* d_ws, size_t ws_size,
                              hipStream_t stream)
{
    (void)in_sizes; (void)n_in; (void)out_size; (void)ws_size;

    const float* h_origin = (const float*)d_in[0];
    const int*   esrc     = (const int*)d_in[1];
    const int*   edst     = (const int*)d_in[2];
    const int*   etyp     = (const int*)d_in[3];
    const float* W_lower  = (const float*)d_in[4];
    const float* b_lower  = (const float*)d_in[5];
    const float* Wl[3]    = {(const float*)d_in[6], (const float*)d_in[8], (const float*)d_in[10]};
    const float* bl[3]    = {(const float*)d_in[7], (const float*)d_in[9], (const float*)d_in[11]};
    const float* W_upper  = (const float*)d_in[12];
    const float* b_upper  = (const float*)d_in[13];
    const float* W_skip   = (const float*)d_in[14];
    const float* b_skip   = (const float*)d_in[15];
    float*       out      = (float*)d_out;

    // Workspace layout
    unsigned short* hob = (unsigned short*)d_ws;          // [NN,512] bf16
    unsigned short* h0  = hob + (size_t)NN * HID;         // [NN,128]
    unsigned short* h1  = h0 + (size_t)NN * LOW;          // [NN,128]
    unsigned short* wlt = h1 + (size_t)NN * LOW;          // [128,512]
    unsigned short* w1t = wlt + (size_t)LOW * HID;        // [128,768] x3
    unsigned short* w2t = w1t + (size_t)LOW * NR * LOW;
    unsigned short* w3t = w2t + (size_t)LOW * NR * LOW;
    unsigned short* wut = w3t + (size_t)LOW * NR * LOW;   // [512,128]
    unsigned short* wst = wut + (size_t)HID * LOW;        // [512,512]
    int* deg      = (int*)(wst + (size_t)HID * HID);      // [NBINS]
    int* rowstart = deg + NBINS;                          // [NBINS+1]
    int* cursor   = rowstart + NBINS + 1;                 // [NBINS]
    int* list     = cursor + NBINS;                       // [NE]
    int* blocksum = list + NE;
    int* blockoff = blocksum + SCAN_NB;
    unsigned short* wtL[3] = {w1t, w2t, w3t};

    const unsigned eBlocks = (unsigned)((NE + 255) / 256);
    const unsigned mBlocks = (unsigned)((NN + 127) / 128);

    // ---- conversions ----
    conv_f32_bf16<<<dim3(2048), dim3(256), 0, stream>>>(
        (const float4*)h_origin, (ushort4*)hob, NN * HID / 4);
    transpose_bf16<<<dim3((HID * LOW + 255) / 256), dim3(256), 0, stream>>>(
        W_lower, wlt, HID, LOW);
    for (int L = 0; L < 3; ++L)
        transpose_bf16<<<dim3((NR * LOW * LOW + 255) / 256), dim3(256), 0, stream>>>(
            Wl[L], wtL[L], NR * LOW, LOW);
    transpose_bf16<<<dim3((LOW * HID + 255) / 256), dim3(256), 0, stream>>>(
        W_upper, wut, LOW, HID);
    transpose_bf16<<<dim3((HID * HID + 255) / 256), dim3(256), 0, stream>>>(
        W_skip, wst, HID, HID);

    // ---- CSR build over (dst, rel) bins ----
    hipMemsetAsync(deg, 0, NBINS * sizeof(int), stream);
    k_hist<<<dim3(eBlocks), dim3(256), 0, stream>>>(edst, etyp, deg, NE);
    k_scan_part<<<dim3(SCAN_NB), dim3(SCAN_BS), 0, stream>>>(deg, blocksum, NBINS);
    k_scan_mid<<<dim3(1), dim3(64), 0, stream>>>(blocksum, blockoff, rowstart, SCAN_NB, NBINS);
    k_scan_final<<<dim3(SCAN_NB), dim3(SCAN_BS), 0, stream>>>(deg, blockoff, rowstart, cursor, NBINS);
    k_fill<<<dim3(eBlocks), dim3(256), 0, stream>>>(esrc, edst, etyp, cursor, list, NE);

    // ---- lower: h0 = relu(hob @ wlt^T + b_lower) ----
    gemm_bf16<<<dim3(1, mBlocks), dim3(256), 0, stream>>>(
        hob, wlt, b_lower, h0, NN, LOW, HID);

    // ---- 3 fused R-GCN layers (ping-pong h0/h1) ----
    unsigned short* hc = h0;
    unsigned short* hn = h1;
    for (int L = 0; L < 3; ++L) {
        rgcn_layer<<<dim3(mBlocks), dim3(256), 0, stream>>>(
            hc, rowstart, list, wtL[L], bl[L], hn);
        unsigned short* t = hc; hc = hn; hn = t;
    }

    // ---- fused output ----
    gemm_out_fused<<<dim3(HID / 128, mBlocks), dim3(256), 0, stream>>>(
        hc, wut, b_upper, hob, wst, b_skip, out, NN);
}

// Round 6
// 857.373 us; speedup vs baseline: 1.8606x; 1.8606x over previous
//
#include <hip/hip_runtime.h>
#include <hip/hip_bf16.h>

#define NN 100000
#define NE 1600000
#define HID 512
#define LOW 128
#define NR  6
#define NBINS (NN * NR)

typedef short  bf16x8 __attribute__((ext_vector_type(8)));
typedef float  f32x4  __attribute__((ext_vector_type(4)));

__device__ __forceinline__ unsigned short f2bf(float x) {
    __hip_bfloat16 h = __float2bfloat16(x);
    return __builtin_bit_cast(unsigned short, h);
}
__device__ __forceinline__ float bf2f(unsigned short u) {
    return __builtin_bit_cast(float, (unsigned int)u << 16);
}

// ---------------------------------------------------------------------------
// Tile staging: global bf16 [rows][Kstride] -> LDS [128][64] bf16 (16 KB),
// rows are 128 B; 16B chunks XOR-swizzled by (row&7) via pre-swizzled SOURCE
// (global_load_lds writes linearly: wave-uniform base + lane*16).
// ---------------------------------------------------------------------------
__device__ __forceinline__ void stage_tile(const unsigned short* __restrict__ G,
                                           int r0, int k0, int Kstride, int Rmax,
                                           char* lds_base, int tid)
{
    #pragma unroll
    for (int is = 0; is < 4; ++is) {
        int L   = is * 4096 + tid * 16;
        int row = L >> 7;
        int c   = ((L >> 4) & 7) ^ (row & 7);
        int gr  = r0 + row;
        gr = (gr < Rmax) ? gr : (Rmax - 1);
        const char* src = (const char*)G + ((size_t)gr * Kstride + k0) * 2 + c * 16;
        __builtin_amdgcn_global_load_lds(
            (const __attribute__((address_space(1))) void*)src,
            (__attribute__((address_space(3))) void*)(lds_base + is * 4096 + (tid & 192) * 16),
            16, 0, 0);
    }
}

__device__ __forceinline__ bf16x8 lds_frag(const char* lds_base, int row, int clog)
{
    return *(const bf16x8*)(lds_base + row * 128 + ((clog ^ (row & 7)) << 4));
}

// ---------------------------------------------------------------------------
// bf16 MFMA GEMM: C(bf16) = relu(A @ Bt^T + bias). 128x128 tile, 4 waves.
// ---------------------------------------------------------------------------
__global__ __launch_bounds__(256, 2)
void gemm_bf16(const unsigned short* __restrict__ A,
               const unsigned short* __restrict__ Bt,
               const float* __restrict__ bias,
               unsigned short* __restrict__ C,
               int M, int N, int K)
{
    __shared__ __align__(16) char lA[16384];
    __shared__ __align__(16) char lB[16384];

    const int tid  = threadIdx.x;
    const int lane = tid & 63;
    const int wid  = tid >> 6;
    const int wm   = wid >> 1;
    const int wn   = wid & 1;
    const int m0   = blockIdx.y * 128;
    const int n0   = blockIdx.x * 128;

    f32x4 acc[4][4] = {};

    for (int k0 = 0; k0 < K; k0 += 64) {
        stage_tile(A,  m0, k0, K, M, lA, tid);
        stage_tile(Bt, n0, k0, K, N, lB, tid);
        __syncthreads();
        #pragma unroll
        for (int kk = 0; kk < 2; ++kk) {
            const int clog = kk * 4 + (lane >> 4);
            bf16x8 af[4], bfr[4];
            #pragma unroll
            for (int i = 0; i < 4; ++i)
                af[i] = lds_frag(lA, wm * 64 + i * 16 + (lane & 15), clog);
            #pragma unroll
            for (int j = 0; j < 4; ++j)
                bfr[j] = lds_frag(lB, wn * 64 + j * 16 + (lane & 15), clog);
            #pragma unroll
            for (int i = 0; i < 4; ++i)
                #pragma unroll
                for (int j = 0; j < 4; ++j)
                    acc[i][j] = __builtin_amdgcn_mfma_f32_16x16x32_bf16(
                        af[i], bfr[j], acc[i][j], 0, 0, 0);
        }
        __syncthreads();
    }

    const int col_l = lane & 15;
    const int rgrp  = lane >> 4;
    #pragma unroll
    for (int i = 0; i < 4; ++i) {
        #pragma unroll
        for (int j = 0; j < 4; ++j) {
            int col  = n0 + wn * 64 + j * 16 + col_l;
            float bv = bias[col];
            #pragma unroll
            for (int r = 0; r < 4; ++r) {
                int row = m0 + wm * 64 + i * 16 + rgrp * 4 + r;
                if (row < M)
                    C[(size_t)row * N + col] = f2bf(fmaxf(acc[i][j][r] + bv, 0.f));
            }
        }
    }
}

// ---------------------------------------------------------------------------
// Fused output: out(f32) = relu(h @ Wut^T + bu) + relu(hob @ Wst^T + bs)
// ---------------------------------------------------------------------------
__global__ __launch_bounds__(256, 2)
void gemm_out_fused(const unsigned short* __restrict__ h,
                    const unsigned short* __restrict__ Wut,
                    const float* __restrict__ bu,
                    const unsigned short* __restrict__ hob,
                    const unsigned short* __restrict__ Wst,
                    const float* __restrict__ bs,
                    float* __restrict__ out, int M)
{
    __shared__ __align__(16) char lA[16384];
    __shared__ __align__(16) char lB[16384];

    const int tid  = threadIdx.x;
    const int lane = tid & 63;
    const int wid  = tid >> 6;
    const int wm   = wid >> 1;
    const int wn   = wid & 1;
    const int m0   = blockIdx.y * 128;
    const int n0   = blockIdx.x * 128;

    f32x4 acc1[4][4] = {};
    f32x4 acc2[4][4] = {};

    for (int k0 = 0; k0 < LOW; k0 += 64) {
        stage_tile(h,   m0, k0, LOW, M,   lA, tid);
        stage_tile(Wut, n0, k0, LOW, HID, lB, tid);
        __syncthreads();
        #pragma unroll
        for (int kk = 0; kk < 2; ++kk) {
            const int clog = kk * 4 + (lane >> 4);
            bf16x8 af[4], bfr[4];
            #pragma unroll
            for (int i = 0; i < 4; ++i)
                af[i] = lds_frag(lA, wm * 64 + i * 16 + (lane & 15), clog);
            #pragma unroll
            for (int j = 0; j < 4; ++j)
                bfr[j] = lds_frag(lB, wn * 64 + j * 16 + (lane & 15), clog);
            #pragma unroll
            for (int i = 0; i < 4; ++i)
                #pragma unroll
                for (int j = 0; j < 4; ++j)
                    acc1[i][j] = __builtin_amdgcn_mfma_f32_16x16x32_bf16(
                        af[i], bfr[j], acc1[i][j], 0, 0, 0);
        }
        __syncthreads();
    }
    for (int k0 = 0; k0 < HID; k0 += 64) {
        stage_tile(hob, m0, k0, HID, M,   lA, tid);
        stage_tile(Wst, n0, k0, HID, HID, lB, tid);
        __syncthreads();
        #pragma unroll
        for (int kk = 0; kk < 2; ++kk) {
            const int clog = kk * 4 + (lane >> 4);
            bf16x8 af[4], bfr[4];
            #pragma unroll
            for (int i = 0; i < 4; ++i)
                af[i] = lds_frag(lA, wm * 64 + i * 16 + (lane & 15), clog);
            #pragma unroll
            for (int j = 0; j < 4; ++j)
                bfr[j] = lds_frag(lB, wn * 64 + j * 16 + (lane & 15), clog);
            #pragma unroll
            for (int i = 0; i < 4; ++i)
                #pragma unroll
                for (int j = 0; j < 4; ++j)
                    acc2[i][j] = __builtin_amdgcn_mfma_f32_16x16x32_bf16(
                        af[i], bfr[j], acc2[i][j], 0, 0, 0);
        }
        __syncthreads();
    }

    const int col_l = lane & 15;
    const int rgrp  = lane >> 4;
    #pragma unroll
    for (int i = 0; i < 4; ++i) {
        #pragma unroll
        for (int j = 0; j < 4; ++j) {
            int col   = n0 + wn * 64 + j * 16 + col_l;
            float bv1 = bu[col], bv2 = bs[col];
            #pragma unroll
            for (int r = 0; r < 4; ++r) {
                int row = m0 + wm * 64 + i * 16 + rgrp * 4 + r;
                if (row < M)
                    out[(size_t)row * HID + col] =
                        fmaxf(acc1[i][j][r] + bv1, 0.f) + fmaxf(acc2[i][j][r] + bv2, 0.f);
            }
        }
    }
}

// ---------------------------------------------------------------------------
// Conversions
// ---------------------------------------------------------------------------
__global__ __launch_bounds__(256)
void conv_f32_bf16(const float4* __restrict__ in, ushort4* __restrict__ out, int n4)
{
    for (int i = blockIdx.x * 256 + threadIdx.x; i < n4; i += gridDim.x * 256) {
        float4 v = in[i];
        ushort4 o;
        o.x = f2bf(v.x); o.y = f2bf(v.y); o.z = f2bf(v.z); o.w = f2bf(v.w);
        out[i] = o;
    }
}

__global__ __launch_bounds__(256)
void transpose_bf16(const float* __restrict__ W, unsigned short* __restrict__ Wt,
                    int R, int C)
{
    int idx = blockIdx.x * 256 + threadIdx.x;
    if (idx < R * C) {
        int r = idx / C, c = idx - r * C;
        Wt[(size_t)c * R + r] = f2bf(W[idx]);
    }
}

// ---------------------------------------------------------------------------
// CSR build keyed by bin = dst*NR + rel. Parallel 3-kernel exclusive scan.
// ---------------------------------------------------------------------------
#define SCAN_VT 8
#define SCAN_BS 256
#define SCAN_CHUNK (SCAN_VT * SCAN_BS)
#define SCAN_NB ((NBINS + SCAN_CHUNK - 1) / SCAN_CHUNK)

__global__ __launch_bounds__(256)
void k_hist(const int* __restrict__ dst, const int* __restrict__ typ,
            int* __restrict__ deg, int E)
{
    int e = blockIdx.x * 256 + threadIdx.x;
    if (e < E) atomicAdd(&deg[dst[e] * NR + typ[e]], 1);
}

__global__ __launch_bounds__(SCAN_BS)
void k_scan_part(const int* __restrict__ deg, int* __restrict__ blocksum, int n)
{
    __shared__ int ps[SCAN_BS];
    const int t = threadIdx.x;
    const int lo = blockIdx.x * SCAN_CHUNK + t * SCAN_VT;
    int s = 0;
    #pragma unroll
    for (int k = 0; k < SCAN_VT; ++k) {
        int i = lo + k;
        if (i < n) s += deg[i];
    }
    ps[t] = s;
    __syncthreads();
    for (int off = SCAN_BS / 2; off > 0; off >>= 1) {
        if (t < off) ps[t] += ps[t + off];
        __syncthreads();
    }
    if (t == 0) blocksum[blockIdx.x] = ps[0];
}

__global__ __launch_bounds__(64)
void k_scan_mid(const int* __restrict__ blocksum, int* __restrict__ blockoff,
                int* __restrict__ rowstart, int nb, int n)
{
    if (threadIdx.x == 0) {
        int run = 0;
        for (int i = 0; i < nb; ++i) { blockoff[i] = run; run += blocksum[i]; }
        rowstart[n] = run;
    }
}

__global__ __launch_bounds__(SCAN_BS)
void k_scan_final(const int* __restrict__ deg, const int* __restrict__ blockoff,
                  int* __restrict__ rowstart, int* __restrict__ cursor, int n)
{
    __shared__ int ps[SCAN_BS];
    const int t = threadIdx.x;
    const int lo = blockIdx.x * SCAN_CHUNK + t * SCAN_VT;
    int local[SCAN_VT];
    int s = 0;
    #pragma unroll
    for (int k = 0; k < SCAN_VT; ++k) {
        int i = lo + k;
        int v = (i < n) ? deg[i] : 0;
        local[k] = v;
        s += v;
    }
    ps[t] = s;
    __syncthreads();
    for (int off = 1; off < SCAN_BS; off <<= 1) {
        int v = (t >= off) ? ps[t - off] : 0;
        __syncthreads();
        ps[t] += v;
        __syncthreads();
    }
    int run = blockoff[blockIdx.x] + ((t > 0) ? ps[t - 1] : 0);
    #pragma unroll
    for (int k = 0; k < SCAN_VT; ++k) {
        int i = lo + k;
        if (i < n) {
            rowstart[i] = run;
            cursor[i]   = run;
            run += local[k];
        }
    }
}

__global__ __launch_bounds__(256)
void k_fill(const int* __restrict__ src, const int* __restrict__ dst,
            const int* __restrict__ typ, int* __restrict__ cursor,
            int* __restrict__ list, int E)
{
    int e = blockIdx.x * 256 + threadIdx.x;
    if (e < E) {
        int pos = atomicAdd(&cursor[dst[e] * NR + typ[e]], 1);
        list[pos] = src[e];
    }
}

// ---------------------------------------------------------------------------
// Gather-aggregate: ONE WAVE per dst node; lane owns channels {2l, 2l+1}.
// All 6 relation segments walked as CONCURRENT chains (clamped indices,
// predicated accumulate) -> 6 independent 256B row reads in flight per wave.
// Wasted iterations load list[0]'s row (L1-hot), no extra HBM traffic.
// ---------------------------------------------------------------------------
__global__ __launch_bounds__(256)
void gather_agg(const unsigned short* __restrict__ h,
                const int* __restrict__ rowstart,
                const int* __restrict__ list,
                unsigned short* __restrict__ S)
{
    const int v = (blockIdx.x * 256 + threadIdx.x) >> 6;
    if (v >= NN) return;
    const int lane = threadIdx.x & 63;
    const ushort2* hp = (const ushort2*)h;

    const int b0 = rowstart[v * NR + 0];
    const int b1 = rowstart[v * NR + 1];
    const int b2 = rowstart[v * NR + 2];
    const int b3 = rowstart[v * NR + 3];
    const int b4 = rowstart[v * NR + 4];
    const int b5 = rowstart[v * NR + 5];
    const int b6 = rowstart[v * NR + 6];
    const int n0 = b1 - b0, n1 = b2 - b1, n2 = b3 - b2;
    const int n3 = b4 - b3, n4 = b5 - b4, n5 = b6 - b5;
    const int kmax = max(max(max(n0, n1), max(n2, n3)), max(n4, n5));

    float ax0 = 0.f, ay0 = 0.f, ax1 = 0.f, ay1 = 0.f, ax2 = 0.f, ay2 = 0.f;
    float ax3 = 0.f, ay3 = 0.f, ax4 = 0.f, ay4 = 0.f, ax5 = 0.f, ay5 = 0.f;

    for (int k = 0; k < kmax; ++k) {
        int i0 = (k < n0) ? (b0 + k) : 0;
        int i1 = (k < n1) ? (b1 + k) : 0;
        int i2 = (k < n2) ? (b2 + k) : 0;
        int i3 = (k < n3) ? (b3 + k) : 0;
        int i4 = (k < n4) ? (b4 + k) : 0;
        int i5 = (k < n5) ? (b5 + k) : 0;
        int s0 = list[i0], s1 = list[i1], s2 = list[i2];
        int s3 = list[i3], s4 = list[i4], s5 = list[i5];
        ushort2 u0 = hp[(size_t)s0 * 64 + lane];
        ushort2 u1 = hp[(size_t)s1 * 64 + lane];
        ushort2 u2 = hp[(size_t)s2 * 64 + lane];
        ushort2 u3 = hp[(size_t)s3 * 64 + lane];
        ushort2 u4 = hp[(size_t)s4 * 64 + lane];
        ushort2 u5 = hp[(size_t)s5 * 64 + lane];
        ax0 += (k < n0) ? bf2f(u0.x) : 0.f;  ay0 += (k < n0) ? bf2f(u0.y) : 0.f;
        ax1 += (k < n1) ? bf2f(u1.x) : 0.f;  ay1 += (k < n1) ? bf2f(u1.y) : 0.f;
        ax2 += (k < n2) ? bf2f(u2.x) : 0.f;  ay2 += (k < n2) ? bf2f(u2.y) : 0.f;
        ax3 += (k < n3) ? bf2f(u3.x) : 0.f;  ay3 += (k < n3) ? bf2f(u3.y) : 0.f;
        ax4 += (k < n4) ? bf2f(u4.x) : 0.f;  ay4 += (k < n4) ? bf2f(u4.y) : 0.f;
        ax5 += (k < n5) ? bf2f(u5.x) : 0.f;  ay5 += (k < n5) ? bf2f(u5.y) : 0.f;
    }

    ushort2* o = (ushort2*)(S + (size_t)v * (NR * LOW));
    ushort2 w;
    w.x = f2bf(ax0); w.y = f2bf(ay0); o[0 * 64 + lane] = w;
    w.x = f2bf(ax1); w.y = f2bf(ay1); o[1 * 64 + lane] = w;
    w.x = f2bf(ax2); w.y = f2bf(ay2); o[2 * 64 + lane] = w;
    w.x = f2bf(ax3); w.y = f2bf(ay3); o[3 * 64 + lane] = w;
    w.x = f2bf(ax4); w.y = f2bf(ay4); o[4 * 64 + lane] = w;
    w.x = f2bf(ax5); w.y = f2bf(ay5); o[5 * 64 + lane] = w;
}

extern "C" void kernel_launch(void* const* d_in, const int* in_sizes, int n_in,
                              void* d_out, int out_size, void* d_ws, size_t ws_size,
                              hipStream_t stream)
{
    (void)in_sizes; (void)n_in; (void)out_size; (void)ws_size;

    const float* h_origin = (const float*)d_in[0];
    const int*   esrc     = (const int*)d_in[1];
    const int*   edst     = (const int*)d_in[2];
    const int*   etyp     = (const int*)d_in[3];
    const float* W_lower  = (const float*)d_in[4];
    const float* b_lower  = (const float*)d_in[5];
    const float* Wl[3]    = {(const float*)d_in[6], (const float*)d_in[8], (const float*)d_in[10]};
    const float* bl[3]    = {(const float*)d_in[7], (const float*)d_in[9], (const float*)d_in[11]};
    const float* W_upper  = (const float*)d_in[12];
    const float* b_upper  = (const float*)d_in[13];
    const float* W_skip   = (const float*)d_in[14];
    const float* b_skip   = (const float*)d_in[15];
    float*       out      = (float*)d_out;

    // Workspace layout
    unsigned short* hob = (unsigned short*)d_ws;          // [NN,512] bf16
    unsigned short* h   = hob + (size_t)NN * HID;         // [NN,128]
    unsigned short* S   = h + (size_t)NN * LOW;           // [NN,768]
    unsigned short* wlt = S + (size_t)NN * NR * LOW;      // [128,512]
    unsigned short* w1t = wlt + (size_t)LOW * HID;
    unsigned short* w2t = w1t + (size_t)LOW * NR * LOW;
    unsigned short* w3t = w2t + (size_t)LOW * NR * LOW;
    unsigned short* wut = w3t + (size_t)LOW * NR * LOW;   // [512,128]
    unsigned short* wst = wut + (size_t)HID * LOW;        // [512,512]
    int* deg      = (int*)(wst + (size_t)HID * HID);      // [NBINS]
    int* rowstart = deg + NBINS;                          // [NBINS+1]
    int* cursor   = rowstart + NBINS + 1;                 // [NBINS]
    int* list     = cursor + NBINS;                       // [NE]
    int* blocksum = list + NE;                            // [SCAN_NB]
    int* blockoff = blocksum + SCAN_NB;                   // [SCAN_NB]
    unsigned short* wtL[3] = {w1t, w2t, w3t};

    const unsigned eBlocks = (unsigned)((NE + 255) / 256);
    const unsigned mBlocks = (unsigned)((NN + 127) / 128);

    // ---- conversions ----
    conv_f32_bf16<<<dim3(2048), dim3(256), 0, stream>>>(
        (const float4*)h_origin, (ushort4*)hob, NN * HID / 4);
    transpose_bf16<<<dim3((HID * LOW + 255) / 256), dim3(256), 0, stream>>>(
        W_lower, wlt, HID, LOW);
    for (int L = 0; L < 3; ++L)
        transpose_bf16<<<dim3((NR * LOW * LOW + 255) / 256), dim3(256), 0, stream>>>(
            Wl[L], wtL[L], NR * LOW, LOW);
    transpose_bf16<<<dim3((LOW * HID + 255) / 256), dim3(256), 0, stream>>>(
        W_upper, wut, LOW, HID);
    transpose_bf16<<<dim3((HID * HID + 255) / 256), dim3(256), 0, stream>>>(
        W_skip, wst, HID, HID);

    // ---- CSR build over (dst, rel) bins ----
    hipMemsetAsync(deg, 0, NBINS * sizeof(int), stream);
    k_hist<<<dim3(eBlocks), dim3(256), 0, stream>>>(edst, etyp, deg, NE);
    k_scan_part<<<dim3(SCAN_NB), dim3(SCAN_BS), 0, stream>>>(deg, blocksum, NBINS);
    k_scan_mid<<<dim3(1), dim3(64), 0, stream>>>(blocksum, blockoff, rowstart, SCAN_NB, NBINS);
    k_scan_final<<<dim3(SCAN_NB), dim3(SCAN_BS), 0, stream>>>(deg, blockoff, rowstart, cursor, NBINS);
    k_fill<<<dim3(eBlocks), dim3(256), 0, stream>>>(esrc, edst, etyp, cursor, list, NE);

    // ---- lower: h = relu(hob @ wlt^T + b_lower) ----
    gemm_bf16<<<dim3(1, mBlocks), dim3(256), 0, stream>>>(
        hob, wlt, b_lower, h, NN, LOW, HID);

    // ---- 3 R-GCN layers ----
    const unsigned gBlocks = (unsigned)((NN * 64 + 255) / 256);
    for (int L = 0; L < 3; ++L) {
        gather_agg<<<dim3(gBlocks), dim3(256), 0, stream>>>(h, rowstart, list, S);
        gemm_bf16<<<dim3(1, mBlocks), dim3(256), 0, stream>>>(
            S, wtL[L], bl[L], h, NN, LOW, NR * LOW);
    }

    // ---- fused output ----
    gemm_out_fused<<<dim3(HID / 128, mBlocks), dim3(256), 0, stream>>>(
        h, wut, b_upper, hob, wst, b_skip, out, NN);
}

// Round 7
// 818.883 us; speedup vs baseline: 1.9481x; 1.0470x over previous
//
#include <hip/hip_runtime.h>
#include <hip/hip_bf16.h>

#define NN 100000
#define NE 1600000
#define HID 512
#define LOW 128
#define NR  6
#define NBINS (NN * NR)

typedef short  bf16x8 __attribute__((ext_vector_type(8)));
typedef float  f32x4  __attribute__((ext_vector_type(4)));

__device__ __forceinline__ unsigned short f2bf(float x) {
    __hip_bfloat16 h = __float2bfloat16(x);
    return __builtin_bit_cast(unsigned short, h);
}
__device__ __forceinline__ float bf2f(unsigned short u) {
    return __builtin_bit_cast(float, (unsigned int)u << 16);
}

// ---------------------------------------------------------------------------
// Tile staging: global bf16 [rows][Kstride] -> LDS [128][64] bf16 (16 KB),
// rows are 128 B; 16B chunks XOR-swizzled by (row&7) via pre-swizzled SOURCE
// (global_load_lds writes linearly: wave-uniform base + lane*16).
// ---------------------------------------------------------------------------
__device__ __forceinline__ void stage_tile(const unsigned short* __restrict__ G,
                                           int r0, int k0, int Kstride, int Rmax,
                                           char* lds_base, int tid)
{
    #pragma unroll
    for (int is = 0; is < 4; ++is) {
        int L   = is * 4096 + tid * 16;
        int row = L >> 7;
        int c   = ((L >> 4) & 7) ^ (row & 7);
        int gr  = r0 + row;
        gr = (gr < Rmax) ? gr : (Rmax - 1);
        const char* src = (const char*)G + ((size_t)gr * Kstride + k0) * 2 + c * 16;
        __builtin_amdgcn_global_load_lds(
            (const __attribute__((address_space(1))) void*)src,
            (__attribute__((address_space(3))) void*)(lds_base + is * 4096 + (tid & 192) * 16),
            16, 0, 0);
    }
}

__device__ __forceinline__ bf16x8 lds_frag(const char* lds_base, int row, int clog)
{
    return *(const bf16x8*)(lds_base + row * 128 + ((clog ^ (row & 7)) << 4));
}

// ---------------------------------------------------------------------------
// bf16 MFMA GEMM: C(bf16) = relu(A @ Bt^T + bias). 128x128 tile, 4 waves.
// ---------------------------------------------------------------------------
__global__ __launch_bounds__(256, 2)
void gemm_bf16(const unsigned short* __restrict__ A,
               const unsigned short* __restrict__ Bt,
               const float* __restrict__ bias,
               unsigned short* __restrict__ C,
               int M, int N, int K)
{
    __shared__ __align__(16) char lA[16384];
    __shared__ __align__(16) char lB[16384];

    const int tid  = threadIdx.x;
    const int lane = tid & 63;
    const int wid  = tid >> 6;
    const int wm   = wid >> 1;
    const int wn   = wid & 1;
    const int m0   = blockIdx.y * 128;
    const int n0   = blockIdx.x * 128;

    f32x4 acc[4][4] = {};

    for (int k0 = 0; k0 < K; k0 += 64) {
        stage_tile(A,  m0, k0, K, M, lA, tid);
        stage_tile(Bt, n0, k0, K, N, lB, tid);
        __syncthreads();
        #pragma unroll
        for (int kk = 0; kk < 2; ++kk) {
            const int clog = kk * 4 + (lane >> 4);
            bf16x8 af[4], bfr[4];
            #pragma unroll
            for (int i = 0; i < 4; ++i)
                af[i] = lds_frag(lA, wm * 64 + i * 16 + (lane & 15), clog);
            #pragma unroll
            for (int j = 0; j < 4; ++j)
                bfr[j] = lds_frag(lB, wn * 64 + j * 16 + (lane & 15), clog);
            #pragma unroll
            for (int i = 0; i < 4; ++i)
                #pragma unroll
                for (int j = 0; j < 4; ++j)
                    acc[i][j] = __builtin_amdgcn_mfma_f32_16x16x32_bf16(
                        af[i], bfr[j], acc[i][j], 0, 0, 0);
        }
        __syncthreads();
    }

    const int col_l = lane & 15;
    const int rgrp  = lane >> 4;
    #pragma unroll
    for (int i = 0; i < 4; ++i) {
        #pragma unroll
        for (int j = 0; j < 4; ++j) {
            int col  = n0 + wn * 64 + j * 16 + col_l;
            float bv = bias[col];
            #pragma unroll
            for (int r = 0; r < 4; ++r) {
                int row = m0 + wm * 64 + i * 16 + rgrp * 4 + r;
                if (row < M)
                    C[(size_t)row * N + col] = f2bf(fmaxf(acc[i][j][r] + bv, 0.f));
            }
        }
    }
}

// ---------------------------------------------------------------------------
// Fused output: out(f32) = relu(h @ Wut^T + bu) + relu(hob @ Wst^T + bs)
// 1-D grid, XCD-bijective swizzle (nwg=3128=8*391): the 4 n-tiles of each
// 128-row hob slab run consecutively on the SAME XCD -> A-slab L2 reuse.
// ---------------------------------------------------------------------------
__global__ __launch_bounds__(256, 2)
void gemm_out_fused(const unsigned short* __restrict__ h,
                    const unsigned short* __restrict__ Wut,
                    const float* __restrict__ bu,
                    const unsigned short* __restrict__ hob,
                    const unsigned short* __restrict__ Wst,
                    const float* __restrict__ bs,
                    float* __restrict__ out, int M)
{
    __shared__ __align__(16) char lA[16384];
    __shared__ __align__(16) char lB[16384];

    const int tid  = threadIdx.x;
    const int lane = tid & 63;
    const int wid  = tid >> 6;
    const int wm   = wid >> 1;
    const int wn   = wid & 1;

    const int nwg  = gridDim.x;            // 3128 = 8 * 391
    const int cpx  = nwg >> 3;
    const int idx  = (blockIdx.x & 7) * cpx + (blockIdx.x >> 3);
    const int m0   = (idx >> 2) * 128;
    const int n0   = (idx & 3) * 128;

    f32x4 acc1[4][4] = {};
    f32x4 acc2[4][4] = {};

    for (int k0 = 0; k0 < LOW; k0 += 64) {
        stage_tile(h,   m0, k0, LOW, M,   lA, tid);
        stage_tile(Wut, n0, k0, LOW, HID, lB, tid);
        __syncthreads();
        #pragma unroll
        for (int kk = 0; kk < 2; ++kk) {
            const int clog = kk * 4 + (lane >> 4);
            bf16x8 af[4], bfr[4];
            #pragma unroll
            for (int i = 0; i < 4; ++i)
                af[i] = lds_frag(lA, wm * 64 + i * 16 + (lane & 15), clog);
            #pragma unroll
            for (int j = 0; j < 4; ++j)
                bfr[j] = lds_frag(lB, wn * 64 + j * 16 + (lane & 15), clog);
            #pragma unroll
            for (int i = 0; i < 4; ++i)
                #pragma unroll
                for (int j = 0; j < 4; ++j)
                    acc1[i][j] = __builtin_amdgcn_mfma_f32_16x16x32_bf16(
                        af[i], bfr[j], acc1[i][j], 0, 0, 0);
        }
        __syncthreads();
    }
    for (int k0 = 0; k0 < HID; k0 += 64) {
        stage_tile(hob, m0, k0, HID, M,   lA, tid);
        stage_tile(Wst, n0, k0, HID, HID, lB, tid);
        __syncthreads();
        #pragma unroll
        for (int kk = 0; kk < 2; ++kk) {
            const int clog = kk * 4 + (lane >> 4);
            bf16x8 af[4], bfr[4];
            #pragma unroll
            for (int i = 0; i < 4; ++i)
                af[i] = lds_frag(lA, wm * 64 + i * 16 + (lane & 15), clog);
            #pragma unroll
            for (int j = 0; j < 4; ++j)
                bfr[j] = lds_frag(lB, wn * 64 + j * 16 + (lane & 15), clog);
            #pragma unroll
            for (int i = 0; i < 4; ++i)
                #pragma unroll
                for (int j = 0; j < 4; ++j)
                    acc2[i][j] = __builtin_amdgcn_mfma_f32_16x16x32_bf16(
                        af[i], bfr[j], acc2[i][j], 0, 0, 0);
        }
        __syncthreads();
    }

    const int col_l = lane & 15;
    const int rgrp  = lane >> 4;
    #pragma unroll
    for (int i = 0; i < 4; ++i) {
        #pragma unroll
        for (int j = 0; j < 4; ++j) {
            int col   = n0 + wn * 64 + j * 16 + col_l;
            float bv1 = bu[col], bv2 = bs[col];
            #pragma unroll
            for (int r = 0; r < 4; ++r) {
                int row = m0 + wm * 64 + i * 16 + rgrp * 4 + r;
                if (row < M)
                    out[(size_t)row * HID + col] =
                        fmaxf(acc1[i][j][r] + bv1, 0.f) + fmaxf(acc2[i][j][r] + bv2, 0.f);
            }
        }
    }
}

// ---------------------------------------------------------------------------
// Conversions
// ---------------------------------------------------------------------------
__global__ __launch_bounds__(256)
void conv_f32_bf16(const float4* __restrict__ in, ushort4* __restrict__ out, int n4)
{
    for (int i = blockIdx.x * 256 + threadIdx.x; i < n4; i += gridDim.x * 256) {
        float4 v = in[i];
        ushort4 o;
        o.x = f2bf(v.x); o.y = f2bf(v.y); o.z = f2bf(v.z); o.w = f2bf(v.w);
        out[i] = o;
    }
}

__global__ __launch_bounds__(256)
void transpose_bf16(const float* __restrict__ W, unsigned short* __restrict__ Wt,
                    int R, int C)
{
    int idx = blockIdx.x * 256 + threadIdx.x;
    if (idx < R * C) {
        int r = idx / C, c = idx - r * C;
        Wt[(size_t)c * R + r] = f2bf(W[idx]);
    }
}

// ---------------------------------------------------------------------------
// CSR build keyed by bin = dst*NR + rel. Parallel 3-kernel exclusive scan.
// ---------------------------------------------------------------------------
#define SCAN_VT 8
#define SCAN_BS 256
#define SCAN_CHUNK (SCAN_VT * SCAN_BS)
#define SCAN_NB ((NBINS + SCAN_CHUNK - 1) / SCAN_CHUNK)

__global__ __launch_bounds__(256)
void k_hist(const int* __restrict__ dst, const int* __restrict__ typ,
            int* __restrict__ deg, int E)
{
    int e = blockIdx.x * 256 + threadIdx.x;
    if (e < E) atomicAdd(&deg[dst[e] * NR + typ[e]], 1);
}

__global__ __launch_bounds__(SCAN_BS)
void k_scan_part(const int* __restrict__ deg, int* __restrict__ blocksum, int n)
{
    __shared__ int ps[SCAN_BS];
    const int t = threadIdx.x;
    const int lo = blockIdx.x * SCAN_CHUNK + t * SCAN_VT;
    int s = 0;
    #pragma unroll
    for (int k = 0; k < SCAN_VT; ++k) {
        int i = lo + k;
        if (i < n) s += deg[i];
    }
    ps[t] = s;
    __syncthreads();
    for (int off = SCAN_BS / 2; off > 0; off >>= 1) {
        if (t < off) ps[t] += ps[t + off];
        __syncthreads();
    }
    if (t == 0) blocksum[blockIdx.x] = ps[0];
}

__global__ __launch_bounds__(64)
void k_scan_mid(const int* __restrict__ blocksum, int* __restrict__ blockoff,
                int* __restrict__ rowstart, int nb, int n)
{
    if (threadIdx.x == 0) {
        int run = 0;
        for (int i = 0; i < nb; ++i) { blockoff[i] = run; run += blocksum[i]; }
        rowstart[n] = run;
    }
}

__global__ __launch_bounds__(SCAN_BS)
void k_scan_final(const int* __restrict__ deg, const int* __restrict__ blockoff,
                  int* __restrict__ rowstart, int* __restrict__ cursor, int n)
{
    __shared__ int ps[SCAN_BS];
    const int t = threadIdx.x;
    const int lo = blockIdx.x * SCAN_CHUNK + t * SCAN_VT;
    int local[SCAN_VT];
    int s = 0;
    #pragma unroll
    for (int k = 0; k < SCAN_VT; ++k) {
        int i = lo + k;
        int v = (i < n) ? deg[i] : 0;
        local[k] = v;
        s += v;
    }
    ps[t] = s;
    __syncthreads();
    for (int off = 1; off < SCAN_BS; off <<= 1) {
        int v = (t >= off) ? ps[t - off] : 0;
        __syncthreads();
        ps[t] += v;
        __syncthreads();
    }
    int run = blockoff[blockIdx.x] + ((t > 0) ? ps[t - 1] : 0);
    #pragma unroll
    for (int k = 0; k < SCAN_VT; ++k) {
        int i = lo + k;
        if (i < n) {
            rowstart[i] = run;
            cursor[i]   = run;
            run += local[k];
        }
    }
}

__global__ __launch_bounds__(256)
void k_fill(const int* __restrict__ src, const int* __restrict__ dst,
            const int* __restrict__ typ, int* __restrict__ cursor,
            int* __restrict__ list, int E)
{
    int e = blockIdx.x * 256 + threadIdx.x;
    if (e < E) {
        int pos = atomicAdd(&cursor[dst[e] * NR + typ[e]], 1);
        list[pos] = src[e];
    }
}

// ---------------------------------------------------------------------------
// Gather-aggregate: HALF-WAVE per dst node; lane owns channels 4c..4c+3
// (ushort4, 32 lanes x 8B = one 256B row). 6 relation chains walked
// concurrently -> each load instruction fetches TWO rows (one per half).
// ---------------------------------------------------------------------------
__global__ __launch_bounds__(256)
void gather_agg(const unsigned short* __restrict__ h,
                const int* __restrict__ rowstart,
                const int* __restrict__ list,
                unsigned short* __restrict__ S)
{
    const int v = (blockIdx.x * 256 + threadIdx.x) >> 5;   // half-wave per node
    if (v >= NN) return;
    const int lane = threadIdx.x & 31;
    const ushort4* hp = (const ushort4*)h;                 // 32 ushort4 per row

    const int b0 = rowstart[v * NR + 0];
    const int b1 = rowstart[v * NR + 1];
    const int b2 = rowstart[v * NR + 2];
    const int b3 = rowstart[v * NR + 3];
    const int b4 = rowstart[v * NR + 4];
    const int b5 = rowstart[v * NR + 5];
    const int b6 = rowstart[v * NR + 6];
    const int n0 = b1 - b0, n1 = b2 - b1, n2 = b3 - b2;
    const int n3 = b4 - b3, n4 = b5 - b4, n5 = b6 - b5;
    const int kmax = max(max(max(n0, n1), max(n2, n3)), max(n4, n5));

    float a0x=0.f,a0y=0.f,a0z=0.f,a0w=0.f, a1x=0.f,a1y=0.f,a1z=0.f,a1w=0.f;
    float a2x=0.f,a2y=0.f,a2z=0.f,a2w=0.f, a3x=0.f,a3y=0.f,a3z=0.f,a3w=0.f;
    float a4x=0.f,a4y=0.f,a4z=0.f,a4w=0.f, a5x=0.f,a5y=0.f,a5z=0.f,a5w=0.f;

    for (int k = 0; k < kmax; ++k) {
        int i0 = (k < n0) ? (b0 + k) : 0;
        int i1 = (k < n1) ? (b1 + k) : 0;
        int i2 = (k < n2) ? (b2 + k) : 0;
        int i3 = (k < n3) ? (b3 + k) : 0;
        int i4 = (k < n4) ? (b4 + k) : 0;
        int i5 = (k < n5) ? (b5 + k) : 0;
        int s0 = list[i0], s1 = list[i1], s2 = list[i2];
        int s3 = list[i3], s4 = list[i4], s5 = list[i5];
        ushort4 u0 = hp[(size_t)s0 * 32 + lane];
        ushort4 u1 = hp[(size_t)s1 * 32 + lane];
        ushort4 u2 = hp[(size_t)s2 * 32 + lane];
        ushort4 u3 = hp[(size_t)s3 * 32 + lane];
        ushort4 u4 = hp[(size_t)s4 * 32 + lane];
        ushort4 u5 = hp[(size_t)s5 * 32 + lane];
        if (k < n0) { a0x += bf2f(u0.x); a0y += bf2f(u0.y); a0z += bf2f(u0.z); a0w += bf2f(u0.w); }
        if (k < n1) { a1x += bf2f(u1.x); a1y += bf2f(u1.y); a1z += bf2f(u1.z); a1w += bf2f(u1.w); }
        if (k < n2) { a2x += bf2f(u2.x); a2y += bf2f(u2.y); a2z += bf2f(u2.z); a2w += bf2f(u2.w); }
        if (k < n3) { a3x += bf2f(u3.x); a3y += bf2f(u3.y); a3z += bf2f(u3.z); a3w += bf2f(u3.w); }
        if (k < n4) { a4x += bf2f(u4.x); a4y += bf2f(u4.y); a4z += bf2f(u4.z); a4w += bf2f(u4.w); }
        if (k < n5) { a5x += bf2f(u5.x); a5y += bf2f(u5.y); a5z += bf2f(u5.z); a5w += bf2f(u5.w); }
    }

    ushort4* o = (ushort4*)(S + (size_t)v * (NR * LOW));
    ushort4 w;
    w.x=f2bf(a0x); w.y=f2bf(a0y); w.z=f2bf(a0z); w.w=f2bf(a0w); o[0*32+lane]=w;
    w.x=f2bf(a1x); w.y=f2bf(a1y); w.z=f2bf(a1z); w.w=f2bf(a1w); o[1*32+lane]=w;
    w.x=f2bf(a2x); w.y=f2bf(a2y); w.z=f2bf(a2z); w.w=f2bf(a2w); o[2*32+lane]=w;
    w.x=f2bf(a3x); w.y=f2bf(a3y); w.z=f2bf(a3z); w.w=f2bf(a3w); o[3*32+lane]=w;
    w.x=f2bf(a4x); w.y=f2bf(a4y); w.z=f2bf(a4z); w.w=f2bf(a4w); o[4*32+lane]=w;
    w.x=f2bf(a5x); w.y=f2bf(a5y); w.z=f2bf(a5z); w.w=f2bf(a5w); o[5*32+lane]=w;
}

extern "C" void kernel_launch(void* const* d_in, const int* in_sizes, int n_in,
                              void* d_out, int out_size, void* d_ws, size_t ws_size,
                              hipStream_t stream)
{
    (void)in_sizes; (void)n_in; (void)out_size; (void)ws_size;

    const float* h_origin = (const float*)d_in[0];
    const int*   esrc     = (const int*)d_in[1];
    const int*   edst     = (const int*)d_in[2];
    const int*   etyp     = (const int*)d_in[3];
    const float* W_lower  = (const float*)d_in[4];
    const float* b_lower  = (const float*)d_in[5];
    const float* Wl[3]    = {(const float*)d_in[6], (const float*)d_in[8], (const float*)d_in[10]};
    const float* bl[3]    = {(const float*)d_in[7], (const float*)d_in[9], (const float*)d_in[11]};
    const float* W_upper  = (const float*)d_in[12];
    const float* b_upper  = (const float*)d_in[13];
    const float* W_skip   = (const float*)d_in[14];
    const float* b_skip   = (const float*)d_in[15];
    float*       out      = (float*)d_out;

    // Workspace layout
    unsigned short* hob = (unsigned short*)d_ws;          // [NN,512] bf16
    unsigned short* h   = hob + (size_t)NN * HID;         // [NN,128]
    unsigned short* S   = h + (size_t)NN * LOW;           // [NN,768]
    unsigned short* wlt = S + (size_t)NN * NR * LOW;      // [128,512]
    unsigned short* w1t = wlt + (size_t)LOW * HID;
    unsigned short* w2t = w1t + (size_t)LOW * NR * LOW;
    unsigned short* w3t = w2t + (size_t)LOW * NR * LOW;
    unsigned short* wut = w3t + (size_t)LOW * NR * LOW;   // [512,128]
    unsigned short* wst = wut + (size_t)HID * LOW;        // [512,512]
    int* deg      = (int*)(wst + (size_t)HID * HID);      // [NBINS]
    int* rowstart = deg + NBINS;                          // [NBINS+1]
    int* cursor   = rowstart + NBINS + 1;                 // [NBINS]
    int* list     = cursor + NBINS;                       // [NE]
    int* blocksum = list + NE;                            // [SCAN_NB]
    int* blockoff = blocksum + SCAN_NB;                   // [SCAN_NB]
    unsigned short* wtL[3] = {w1t, w2t, w3t};

    const unsigned eBlocks = (unsigned)((NE + 255) / 256);
    const unsigned mBlocks = (unsigned)((NN + 127) / 128);

    // ---- conversions ----
    conv_f32_bf16<<<dim3(2048), dim3(256), 0, stream>>>(
        (const float4*)h_origin, (ushort4*)hob, NN * HID / 4);
    transpose_bf16<<<dim3((HID * LOW + 255) / 256), dim3(256), 0, stream>>>(
        W_lower, wlt, HID, LOW);
    for (int L = 0; L < 3; ++L)
        transpose_bf16<<<dim3((NR * LOW * LOW + 255) / 256), dim3(256), 0, stream>>>(
            Wl[L], wtL[L], NR * LOW, LOW);
    transpose_bf16<<<dim3((LOW * HID + 255) / 256), dim3(256), 0, stream>>>(
        W_upper, wut, LOW, HID);
    transpose_bf16<<<dim3((HID * HID + 255) / 256), dim3(256), 0, stream>>>(
        W_skip, wst, HID, HID);

    // ---- CSR build over (dst, rel) bins ----
    hipMemsetAsync(deg, 0, NBINS * sizeof(int), stream);
    k_hist<<<dim3(eBlocks), dim3(256), 0, stream>>>(edst, etyp, deg, NE);
    k_scan_part<<<dim3(SCAN_NB), dim3(SCAN_BS), 0, stream>>>(deg, blocksum, NBINS);
    k_scan_mid<<<dim3(1), dim3(64), 0, stream>>>(blocksum, blockoff, rowstart, SCAN_NB, NBINS);
    k_scan_final<<<dim3(SCAN_NB), dim3(SCAN_BS), 0, stream>>>(deg, blockoff, rowstart, cursor, NBINS);
    k_fill<<<dim3(eBlocks), dim3(256), 0, stream>>>(esrc, edst, etyp, cursor, list, NE);

    // ---- lower: h = relu(hob @ wlt^T + b_lower) ----
    gemm_bf16<<<dim3(1, mBlocks), dim3(256), 0, stream>>>(
        hob, wlt, b_lower, h, NN, LOW, HID);

    // ---- 3 R-GCN layers ----
    const unsigned gBlocks = (unsigned)(((size_t)NN * 32 + 255) / 256);
    for (int L = 0; L < 3; ++L) {
        gather_agg<<<dim3(gBlocks), dim3(256), 0, stream>>>(h, rowstart, list, S);
        gemm_bf16<<<dim3(1, mBlocks), dim3(256), 0, stream>>>(
            S, wtL[L], bl[L], h, NN, LOW, NR * LOW);
    }

    // ---- fused output (1-D grid, XCD swizzle inside) ----
    gemm_out_fused<<<dim3((HID / 128) * mBlocks), dim3(256), 0, stream>>>(
        h, wut, b_upper, hob, wst, b_skip, out, NN);
}